// Round 19
// baseline (111.440 us; speedup 1.0000x reference)
//
#include <hip/hip_runtime.h>
#include <hip/hip_bf16.h>
#include <stdint.h>

// Problem constants: B=4, N=2048, D=512, H=8, HD=64
#define NTOK 2048
#define DIN  512
// 0.125 (1/sqrt(64)) * log2(e): folded into Q so softmax uses exp2
#define QSCALE 0.18033688011112042f

typedef __attribute__((ext_vector_type(8))) short bf16x8;
typedef __attribute__((ext_vector_type(4))) short bf16x4;
typedef __attribute__((ext_vector_type(4))) float f32x4;

#define MFMA16(a, b, c) __builtin_amdgcn_mfma_f32_16x16x32_bf16((a), (b), (c), 0, 0, 0)

union u4bf8 { uint4 u; bf16x8 h; };

static __device__ __forceinline__ short f2bf(float f) {
  union { float f; uint32_t u; } v; v.f = f;
  uint32_t r = (v.u + 0x7FFFu + ((v.u >> 16) & 1u)) >> 16;
  return (short)r;
}

// ---- fused prep: [0,4096) x->bf16 | [4096,4864) W transpose | [4864,21248) adj->bitmask
__global__ __launch_bounds__(256) void k_prep(const float* __restrict__ x, short* __restrict__ xb,
                                              const float* __restrict__ Wq,
                                              const float* __restrict__ Wk,
                                              const float* __restrict__ Wv,
                                              short* __restrict__ Wt,
                                              const float* __restrict__ adj,
                                              unsigned long long* __restrict__ m64) {
  const int bid = blockIdx.x;
  const int tid = threadIdx.x;
  if (bid < 4096) {
    size_t i = (size_t)bid * 256 + tid;  // chunk of 4 floats
    const float4 v = *(const float4*)(x + i * 4);
    bf16x4 h;
    h[0] = f2bf(v.x); h[1] = f2bf(v.y); h[2] = f2bf(v.z); h[3] = f2bf(v.w);
    *(bf16x4*)(xb + i * 4) = h;
  } else if (bid < 4864) {
    const int b2 = bid - 4096;
    const int z = b2 >> 8, rem = b2 & 255;
    const float* W = (z == 0) ? Wq : ((z == 1) ? Wk : Wv);
    short* Wo = Wt + (size_t)z * DIN * DIN;
    __shared__ float tile[32][33];
    const int bo = (rem & 15) * 32, bc = (rem >> 4) * 32;
    const int tx = tid & 31, ty = tid >> 5;  // 32 x 8
#pragma unroll
    for (int q = 0; q < 4; ++q)
      tile[ty + q * 8][tx] = W[(bc + ty + q * 8) * DIN + bo + tx];
    __syncthreads();
#pragma unroll
    for (int q = 0; q < 4; ++q)
      Wo[(bo + ty + q * 8) * DIN + bc + tx] = f2bf(tile[tx][ty + q * 8]);
  } else {
    const int mb = bid - 4864;
    const int wid = ((mb * 256 + tid) >> 6);
    const int lane = tid & 63;
    const int i = wid >> 5, wd = wid & 31;  // 2048 rows x 32 words
    float a = adj[(size_t)i * NTOK + wd * 64 + lane];
    unsigned long long b = __ballot(a != 0.0f);
    if (lane == 0) m64[i * 32 + wd] = b;
  }
}

// ---- fused QKV projection GEMM with reg-prefetch + double-buffered LDS:
// [8192x512] x [512x512] (+bias). z=0 -> Q (scaled) [bh][n][d]; z=1 -> K; z=2 -> V^T [bh][d][n]
__global__ __launch_bounds__(256, 3) void k_qkv(const short* __restrict__ xb,
                                                const short* __restrict__ Wt,
                                                const float* __restrict__ bq,
                                                const float* __restrict__ bk,
                                                const float* __restrict__ bv,
                                                short* __restrict__ Qb, short* __restrict__ Kb,
                                                short* __restrict__ Vb) {
  __shared__ short As[2][128 * 40];  // [m][k] pad 40
  __shared__ short Bs[2][128 * 40];  // [o][k]
  const int z = blockIdx.z;
  const short* Wz = Wt + z * DIN * DIN;
  const float* bias = (z == 0) ? bq : ((z == 1) ? bk : bv);
  const int mbase = blockIdx.x * 128, nbase = blockIdx.y * 128;
  const int tid = threadIdx.x;
  const int lane = tid & 63, w = tid >> 6;
  const int wr = w >> 1, wc = w & 1;
  const int lrow = lane & 15, lgrp = lane >> 4;
  const int ra = tid >> 2, ca = tid & 3;

  f32x4 acc[4][4];
#pragma unroll
  for (int a = 0; a < 4; ++a)
#pragma unroll
    for (int b = 0; b < 4; ++b) acc[a][b] = (f32x4){0.f, 0.f, 0.f, 0.f};

  // prologue: stage k-step 0
  uint4 pA[2], pB[2];
#pragma unroll
  for (int u = 0; u < 2; ++u) {
    pA[u] = *(const uint4*)(xb + (size_t)(mbase + ra + u * 64) * DIN + ca * 8);
    pB[u] = *(const uint4*)(Wz + (size_t)(nbase + ra + u * 64) * DIN + ca * 8);
  }
#pragma unroll
  for (int u = 0; u < 2; ++u) {
    *(uint4*)(&As[0][(ra + u * 64) * 40 + ca * 8]) = pA[u];
    *(uint4*)(&Bs[0][(ra + u * 64) * 40 + ca * 8]) = pB[u];
  }
  __syncthreads();

  for (int t = 0; t < 16; ++t) {
    const int cur = t & 1, nxt = cur ^ 1;
    if (t < 15) {
      const int kb = (t + 1) * 32;
#pragma unroll
      for (int u = 0; u < 2; ++u) {
        pA[u] = *(const uint4*)(xb + (size_t)(mbase + ra + u * 64) * DIN + kb + ca * 8);
        pB[u] = *(const uint4*)(Wz + (size_t)(nbase + ra + u * 64) * DIN + kb + ca * 8);
      }
    }
    bf16x8 af[4], bf[4];
#pragma unroll
    for (int mi = 0; mi < 4; ++mi)
      af[mi] = *(bf16x8*)(&As[cur][(wr * 64 + mi * 16 + lrow) * 40 + lgrp * 8]);
#pragma unroll
    for (int ni = 0; ni < 4; ++ni)
      bf[ni] = *(bf16x8*)(&Bs[cur][(wc * 64 + ni * 16 + lrow) * 40 + lgrp * 8]);
#pragma unroll
    for (int mi = 0; mi < 4; ++mi)
#pragma unroll
      for (int ni = 0; ni < 4; ++ni) acc[mi][ni] = MFMA16(af[mi], bf[ni], acc[mi][ni]);

    if (t < 15) {
#pragma unroll
      for (int u = 0; u < 2; ++u) {
        *(uint4*)(&As[nxt][(ra + u * 64) * 40 + ca * 8]) = pA[u];
        *(uint4*)(&Bs[nxt][(ra + u * 64) * 40 + ca * 8]) = pB[u];
      }
      __syncthreads();  // single barrier: cur-buffer reads all happened before it
    }
  }

#pragma unroll
  for (int ni = 0; ni < 4; ++ni) {
    int go = nbase + wc * 64 + ni * 16 + lrow;  // output col = h*64+d
    float bv_ = bias[go];
    int h = go >> 6, d = go & 63;
#pragma unroll
    for (int mi = 0; mi < 4; ++mi) {
#pragma unroll
      for (int v = 0; v < 4; ++v) {
        int gm = mbase + wr * 64 + mi * 16 + lgrp * 4 + v;  // row = b*2048+n
        int b = gm >> 11, n = gm & 2047;
        int bh = b * 8 + h;
        float val = acc[mi][ni][v] + bv_;
        if (z == 0)
          Qb[(size_t)bh * (NTOK * 64) + n * 64 + d] = f2bf(val * QSCALE);
        else if (z == 1)
          Kb[(size_t)bh * (NTOK * 64) + n * 64 + d] = f2bf(val);
        else
          Vb[(size_t)bh * (64 * NTOK) + d * NTOK + n] = f2bf(val);
      }
    }
  }
}

// ---- masked flash attention: R13/R18 core with column-interleaved V LDS layout.
// Within each 32-j half, 4-short chunks stored [c0 c4 c1 c5 c2 c6 c3 c7] so a
// lane's two PV chunks (c=lgrp, c=lgrp+4) are one contiguous b128 read.
// LDS ops per thread-jt: 14 -> 11. Everything else identical to R18's k_attn.
// grid (itile=32, bh=32), 512 thr; wave = (wi i-group of 16 rows, wj j-half).
__global__ __launch_bounds__(512, 8) void k_attn(const short* __restrict__ Qb,
                                                 const short* __restrict__ Kb,
                                                 const short* __restrict__ Vb,
                                                 const unsigned long long* __restrict__ m64,
                                                 float* __restrict__ out) {
  // main loop: Ks [64][72] + Vs [64][72] = 18432B; epilogue aliases ored 16KB + lsum 512B
  __shared__ char smem[18432];
  short* Ks = (short*)smem;
  short* Vs = (short*)(smem + 9216);
  f32x4* ored = (f32x4*)smem;
  float* lsum = (float*)(smem + 16384);

  const int itile = blockIdx.x, bh = blockIdx.y;
  const int ibase = itile * 64;
  const int tid = threadIdx.x, lane = tid & 63, w = tid >> 6;
  const int wi = w >> 1, wj = w & 1;  // i-group (16 rows), j-half (32 of each 64-tile)
  const int lrow = lane & 15, lgrp = lane >> 4;

  const short* Qp = Qb + (size_t)bh * (NTOK * 64);
  const short* Kp = Kb + (size_t)bh * (NTOK * 64);
  const short* Vp = Vb + (size_t)bh * (64 * NTOK);

  // Q fragments for this wave's 16-row i-group
  const int qrow = ibase + wi * 16 + lrow;
  bf16x8 qa[2];
  qa[0] = *(const bf16x8*)(Qp + (size_t)qrow * 64 + lgrp * 8);
  qa[1] = *(const bf16x8*)(Qp + (size_t)qrow * 64 + 32 + lgrp * 8);
  const unsigned long long* mword = m64 + (size_t)qrow * 32;

  // staging: thread (r0 = tid>>3, s0 = tid&7), one 16B K piece + one 16B V piece.
  // V LDS offsets (column-interleave): global chunk pair {2t, 2t+1} of half s0>>2
  // lands at o1 = half*32 + (t<2 ? 16t : 16t-28), o2 = o1 + 8 (two b64 writes).
  const int r0 = tid >> 3, s0 = tid & 7;
  const int vt = s0 & 3;
  const int vo1 = (s0 >> 2) * 32 + ((vt < 2) ? 16 * vt : 16 * vt - 28);

  f32x4 oacc[4];  // [dn]: O[i = wi*16+lgrp*4+v][d = dn*16+lrow], partial over wave's j-half
#pragma unroll
  for (int dn = 0; dn < 4; ++dn) oacc[dn] = (f32x4){0.f, 0.f, 0.f, 0.f};
  float lrun = 0.f;  // row-sum partial (lane's row qrow, wave's j-half)

  // prologue: load tile 0 + mask word, write LDS, barrier
  uint4 pfK = *(const uint4*)(Kp + (size_t)r0 * 64 + s0 * 8);
  uint4 pfV = *(const uint4*)(Vp + (size_t)r0 * NTOK + s0 * 8);
  unsigned long long mw = mword[0];
  *(uint4*)(Ks + r0 * 72 + s0 * 8) = pfK;
  {
    uint2 w1; w1.x = pfV.x; w1.y = pfV.y;
    uint2 w2; w2.x = pfV.z; w2.y = pfV.w;
    *(uint2*)(Vs + r0 * 72 + vo1) = w1;
    *(uint2*)(Vs + r0 * 72 + vo1 + 8) = w2;
  }
  __syncthreads();

  for (int jt = 0; jt < 32; ++jt) {
    // issue next tile's global loads; latency hides under this tile's compute
    unsigned long long mwn = 0ull;
    if (jt < 31) {
      const int jn = (jt + 1) * 64;
      pfK = *(const uint4*)(Kp + (size_t)(jn + r0) * 64 + s0 * 8);
      pfV = *(const uint4*)(Vp + (size_t)r0 * NTOK + jn + s0 * 8);
      mwn = mword[jt + 1];
    }

    // S^T = K Q^T over this wave's j-half; P packed straight into registers.
    // lane holds S[j = jt*64 + wj*32 + jsub*16 + lgrp*4 + r][i = qrow]
    uint32_t pk[2][2];  // [jsub][word]
#pragma unroll
    for (int jsub = 0; jsub < 2; ++jsub) {
      const int krow = (wj * 32 + jsub * 16 + lrow) * 72;
      bf16x8 kf0 = *(bf16x8*)(Ks + krow + lgrp * 8);
      bf16x8 kf1 = *(bf16x8*)(Ks + krow + 32 + lgrp * 8);
      f32x4 zz = (f32x4){0.f, 0.f, 0.f, 0.f};
      zz = MFMA16(kf0, qa[0], zz);
      zz = MFMA16(kf1, qa[1], zz);
      const uint32_t bits = (uint32_t)(mw >> (wj * 32 + jsub * 16 + lgrp * 4));
      float p0 = (bits & 1u) ? exp2f(zz[0]) : 0.f;
      float p1 = (bits & 2u) ? exp2f(zz[1]) : 0.f;
      float p2 = (bits & 4u) ? exp2f(zz[2]) : 0.f;
      float p3 = (bits & 8u) ? exp2f(zz[3]) : 0.f;
      lrun += (p0 + p1) + (p2 + p3);
      uint32_t w0, w1;
      asm("v_cvt_pk_bf16_f32 %0, %1, %2" : "=v"(w0) : "v"(p0), "v"(p1));
      asm("v_cvt_pk_bf16_f32 %0, %1, %2" : "=v"(w1) : "v"(p2), "v"(p3));
      pk[jsub][0] = w0;
      pk[jsub][1] = w1;
    }

    // O += P V: k-slot t<4 = jsub0 (j = wj*32+lgrp*4+t), t>=4 = jsub1 (+16).
    // Interleaved V layout -> both chunks in ONE b128 at wj*32 + lgrp*8.
#pragma unroll
    for (int dn = 0; dn < 4; ++dn) {
      u4bf8 vb;
      vb.u = *(const uint4*)(Vs + (dn * 16 + lrow) * 72 + wj * 32 + lgrp * 8);
      u4bf8 pa;
      pa.u = (uint4){pk[0][0], pk[0][1], pk[1][0], pk[1][1]};
      oacc[dn] = MFMA16(pa.h, vb.h, oacc[dn]);
    }

    if (jt < 31) {
      __syncthreads();  // all waves done reading Ks/Vs
      *(uint4*)(Ks + r0 * 72 + s0 * 8) = pfK;
      {
        uint2 w1; w1.x = pfV.x; w1.y = pfV.y;
        uint2 w2; w2.x = pfV.z; w2.y = pfV.w;
        *(uint2*)(Vs + r0 * 72 + vo1) = w1;
        *(uint2*)(Vs + r0 * 72 + vo1 + 8) = w2;
      }
      mw = mwn;
      __syncthreads();  // writes visible
    }
  }

  __syncthreads();  // done with Ks/Vs; smem becomes ored/lsum

  // ---- epilogue: reduce across the wj wave pair, normalize, store ----
  {
    float s = lrun;
    s += __shfl_xor(s, 16);
    s += __shfl_xor(s, 32);
    if (lane < 16) lsum[w * 16 + lane] = s;  // w = wi*2+wj
  }
  if (wj == 1) {
#pragma unroll
    for (int dn = 0; dn < 4; ++dn) ored[(wi * 4 + dn) * 64 + lane] = oacc[dn];
  }
  __syncthreads();

  if (wj == 0) {
    const int b = bh >> 3, h = bh & 7;
    const f32x4 la = *(const f32x4*)&lsum[(wi * 2 + 0) * 16 + lgrp * 4];
    const f32x4 lb = *(const f32x4*)&lsum[(wi * 2 + 1) * 16 + lgrp * 4];
    float inv[4];
#pragma unroll
    for (int v = 0; v < 4; ++v) inv[v] = 1.0f / (la[v] + lb[v]);
#pragma unroll
    for (int dn = 0; dn < 4; ++dn) {
      f32x4 s = oacc[dn] + ored[(wi * 4 + dn) * 64 + lane];
#pragma unroll
      for (int v = 0; v < 4; ++v) {
        int i = ibase + wi * 16 + lgrp * 4 + v;
        out[(size_t)(b * NTOK + i) * DIN + h * 64 + dn * 16 + lrow] = s[v] * inv[v];
      }
    }
  }
}

extern "C" void kernel_launch(void* const* d_in, const int* in_sizes, int n_in,
                              void* d_out, int out_size, void* d_ws, size_t ws_size,
                              hipStream_t stream) {
  const float* x   = (const float*)d_in[0];
  const float* adj = (const float*)d_in[1];
  const float* Wq  = (const float*)d_in[2];
  const float* bq  = (const float*)d_in[3];
  const float* Wk  = (const float*)d_in[4];
  const float* bk  = (const float*)d_in[5];
  const float* Wv  = (const float*)d_in[6];
  const float* bv  = (const float*)d_in[7];
  float* out = (float*)d_out;

  char* ws = (char*)d_ws;
  short* Qb = (short*)(ws);                          // 8 MB  [bh][n][d]
  short* Kb = (short*)(ws + (8u << 20));             // 8 MB  [bh][n][d]
  short* Vb = (short*)(ws + (16u << 20));            // 8 MB  [bh][d][n]
  short* Wt = (short*)(ws + (24u << 20));            // 1.5 MB [3][512][512]
  unsigned long long* m64 = (unsigned long long*)(ws + (26u << 20));  // 512 KB
  short* xb = (short*)d_out;  // 8 MB scratch inside the 16.8 MB output buffer;
                              // fully consumed by k_qkv before k_attn overwrites out.

  k_prep<<<21248, 256, 0, stream>>>(x, xb, Wq, Wk, Wv, Wt, adj, m64);
  k_qkv<<<dim3(64, 4, 3), 256, 0, stream>>>(xb, Wt, bq, bk, bv, Qb, Kb, Vb);
  k_attn<<<dim3(32, 32), 512, 0, stream>>>(Qb, Kb, Vb, m64, out);
}

// Round 20
// 110.348 us; speedup vs baseline: 1.0099x; 1.0099x over previous
//
#include <hip/hip_runtime.h>
#include <hip/hip_bf16.h>
#include <stdint.h>

// Problem constants: B=4, N=2048, D=512, H=8, HD=64
#define NTOK 2048
#define DIN  512
// 0.125 (1/sqrt(64)) * log2(e): folded into Q so softmax uses exp2
#define QSCALE 0.18033688011112042f

typedef __attribute__((ext_vector_type(8))) short bf16x8;
typedef __attribute__((ext_vector_type(4))) short bf16x4;
typedef __attribute__((ext_vector_type(4))) float f32x4;

#define MFMA16(a, b, c) __builtin_amdgcn_mfma_f32_16x16x32_bf16((a), (b), (c), 0, 0, 0)

union u4bf8 { uint4 u; bf16x8 h; };

static __device__ __forceinline__ short f2bf(float f) {
  union { float f; uint32_t u; } v; v.f = f;
  uint32_t r = (v.u + 0x7FFFu + ((v.u >> 16) & 1u)) >> 16;
  return (short)r;
}

// ---- fused prep: [0,4096) x->bf16 | [4096,4864) W transpose | [4864,21248) adj->bitmask
__global__ __launch_bounds__(256) void k_prep(const float* __restrict__ x, short* __restrict__ xb,
                                              const float* __restrict__ Wq,
                                              const float* __restrict__ Wk,
                                              const float* __restrict__ Wv,
                                              short* __restrict__ Wt,
                                              const float* __restrict__ adj,
                                              unsigned long long* __restrict__ m64) {
  const int bid = blockIdx.x;
  const int tid = threadIdx.x;
  if (bid < 4096) {
    // x f32 -> bf16 (xb lives in d_out scratch; k_attn overwrites later)
    size_t i = (size_t)bid * 256 + tid;  // chunk of 4 floats
    const float4 v = *(const float4*)(x + i * 4);
    bf16x4 h;
    h[0] = f2bf(v.x); h[1] = f2bf(v.y); h[2] = f2bf(v.z); h[3] = f2bf(v.w);
    *(bf16x4*)(xb + i * 4) = h;
  } else if (bid < 4864) {
    // W transpose + convert: Wt[z][o][c] = W[z][c][o]
    const int b2 = bid - 4096;
    const int z = b2 >> 8, rem = b2 & 255;
    const float* W = (z == 0) ? Wq : ((z == 1) ? Wk : Wv);
    short* Wo = Wt + (size_t)z * DIN * DIN;
    __shared__ float tile[32][33];
    const int bo = (rem & 15) * 32, bc = (rem >> 4) * 32;
    const int tx = tid & 31, ty = tid >> 5;  // 32 x 8
#pragma unroll
    for (int q = 0; q < 4; ++q)
      tile[ty + q * 8][tx] = W[(bc + ty + q * 8) * DIN + bo + tx];
    __syncthreads();
#pragma unroll
    for (int q = 0; q < 4; ++q)
      Wo[(bo + ty + q * 8) * DIN + bc + tx] = f2bf(tile[tx][ty + q * 8]);
  } else {
    // adjacency -> bitmask: m64[i][w] bit j = (adj[i][w*64+j] != 0)
    const int mb = bid - 4864;
    const int wid = ((mb * 256 + tid) >> 6);
    const int lane = tid & 63;
    const int i = wid >> 5, wd = wid & 31;  // 2048 rows x 32 words
    float a = adj[(size_t)i * NTOK + wd * 64 + lane];
    unsigned long long b = __ballot(a != 0.0f);
    if (lane == 0) m64[i * 32 + wd] = b;
  }
}

// ---- fused QKV projection GEMM with reg-prefetch + double-buffered LDS:
// [8192x512] x [512x512] (+bias). z=0 -> Q (scaled) [bh][n][d]; z=1 -> K; z=2 -> V^T [bh][d][n]
__global__ __launch_bounds__(256, 3) void k_qkv(const short* __restrict__ xb,
                                                const short* __restrict__ Wt,
                                                const float* __restrict__ bq,
                                                const float* __restrict__ bk,
                                                const float* __restrict__ bv,
                                                short* __restrict__ Qb, short* __restrict__ Kb,
                                                short* __restrict__ Vb) {
  __shared__ short As[2][128 * 40];  // [m][k] pad 40
  __shared__ short Bs[2][128 * 40];  // [o][k]
  const int z = blockIdx.z;
  const short* Wz = Wt + z * DIN * DIN;
  const float* bias = (z == 0) ? bq : ((z == 1) ? bk : bv);
  const int mbase = blockIdx.x * 128, nbase = blockIdx.y * 128;
  const int tid = threadIdx.x;
  const int lane = tid & 63, w = tid >> 6;
  const int wr = w >> 1, wc = w & 1;
  const int lrow = lane & 15, lgrp = lane >> 4;
  const int ra = tid >> 2, ca = tid & 3;

  f32x4 acc[4][4];
#pragma unroll
  for (int a = 0; a < 4; ++a)
#pragma unroll
    for (int b = 0; b < 4; ++b) acc[a][b] = (f32x4){0.f, 0.f, 0.f, 0.f};

  // prologue: stage k-step 0
  uint4 pA[2], pB[2];
#pragma unroll
  for (int u = 0; u < 2; ++u) {
    pA[u] = *(const uint4*)(xb + (size_t)(mbase + ra + u * 64) * DIN + ca * 8);
    pB[u] = *(const uint4*)(Wz + (size_t)(nbase + ra + u * 64) * DIN + ca * 8);
  }
#pragma unroll
  for (int u = 0; u < 2; ++u) {
    *(uint4*)(&As[0][(ra + u * 64) * 40 + ca * 8]) = pA[u];
    *(uint4*)(&Bs[0][(ra + u * 64) * 40 + ca * 8]) = pB[u];
  }
  __syncthreads();

  for (int t = 0; t < 16; ++t) {
    const int cur = t & 1, nxt = cur ^ 1;
    if (t < 15) {
      const int kb = (t + 1) * 32;
#pragma unroll
      for (int u = 0; u < 2; ++u) {
        pA[u] = *(const uint4*)(xb + (size_t)(mbase + ra + u * 64) * DIN + kb + ca * 8);
        pB[u] = *(const uint4*)(Wz + (size_t)(nbase + ra + u * 64) * DIN + kb + ca * 8);
      }
    }
    bf16x8 af[4], bf[4];
#pragma unroll
    for (int mi = 0; mi < 4; ++mi)
      af[mi] = *(bf16x8*)(&As[cur][(wr * 64 + mi * 16 + lrow) * 40 + lgrp * 8]);
#pragma unroll
    for (int ni = 0; ni < 4; ++ni)
      bf[ni] = *(bf16x8*)(&Bs[cur][(wc * 64 + ni * 16 + lrow) * 40 + lgrp * 8]);
#pragma unroll
    for (int mi = 0; mi < 4; ++mi)
#pragma unroll
      for (int ni = 0; ni < 4; ++ni) acc[mi][ni] = MFMA16(af[mi], bf[ni], acc[mi][ni]);

    if (t < 15) {
#pragma unroll
      for (int u = 0; u < 2; ++u) {
        *(uint4*)(&As[nxt][(ra + u * 64) * 40 + ca * 8]) = pA[u];
        *(uint4*)(&Bs[nxt][(ra + u * 64) * 40 + ca * 8]) = pB[u];
      }
      __syncthreads();  // single barrier: cur-buffer reads all happened before it
    }
  }

#pragma unroll
  for (int ni = 0; ni < 4; ++ni) {
    int go = nbase + wc * 64 + ni * 16 + lrow;  // output col = h*64+d
    float bv_ = bias[go];
    int h = go >> 6, d = go & 63;
#pragma unroll
    for (int mi = 0; mi < 4; ++mi) {
#pragma unroll
      for (int v = 0; v < 4; ++v) {
        int gm = mbase + wr * 64 + mi * 16 + lgrp * 4 + v;  // row = b*2048+n
        int b = gm >> 11, n = gm & 2047;
        int bh = b * 8 + h;
        float val = acc[mi][ni][v] + bv_;
        if (z == 0)
          Qb[(size_t)bh * (NTOK * 64) + n * 64 + d] = f2bf(val * QSCALE);
        else if (z == 1)
          Kb[(size_t)bh * (NTOK * 64) + n * 64 + d] = f2bf(val);
        else
          Vb[(size_t)bh * (64 * NTOK) + d * NTOK + n] = f2bf(val);
      }
    }
  }
}

// ---- masked flash attention (R13/R18, best-measured 81.4-82.0us): 8 waves /
// 512 thr, padded-72 LDS, linear block map, async reg-prefetch, P-in-registers
// (permuted-k PV), no-max softmax via exp2, cross-wave wj-pair epilogue.
// Structural floor: dependency-bound (~60% VALU, ~60% LDS-pipe, 17% MFMA);
// 13 structural variants (occupancy 20-81%, barriers 32-62, conflicts 16K-12.6M)
// all land 81-92us. grid (itile=32, bh=32); wave = (wi i-group, wj j-half).
__global__ __launch_bounds__(512, 8) void k_attn(const short* __restrict__ Qb,
                                                 const short* __restrict__ Kb,
                                                 const short* __restrict__ Vb,
                                                 const unsigned long long* __restrict__ m64,
                                                 float* __restrict__ out) {
  // main loop: Ks [64][72] + Vs [64][72] = 18432B; epilogue aliases ored 16KB + lsum 512B
  __shared__ char smem[18432];
  short* Ks = (short*)smem;
  short* Vs = (short*)(smem + 9216);
  f32x4* ored = (f32x4*)smem;
  float* lsum = (float*)(smem + 16384);

  const int itile = blockIdx.x, bh = blockIdx.y;
  const int ibase = itile * 64;
  const int tid = threadIdx.x, lane = tid & 63, w = tid >> 6;
  const int wi = w >> 1, wj = w & 1;  // i-group (16 rows), j-half (32 of each 64-tile)
  const int lrow = lane & 15, lgrp = lane >> 4;

  const short* Qp = Qb + (size_t)bh * (NTOK * 64);
  const short* Kp = Kb + (size_t)bh * (NTOK * 64);
  const short* Vp = Vb + (size_t)bh * (64 * NTOK);

  // Q fragments for this wave's 16-row i-group
  const int qrow = ibase + wi * 16 + lrow;
  bf16x8 qa[2];
  qa[0] = *(const bf16x8*)(Qp + (size_t)qrow * 64 + lgrp * 8);
  qa[1] = *(const bf16x8*)(Qp + (size_t)qrow * 64 + 32 + lgrp * 8);
  const unsigned long long* mword = m64 + (size_t)qrow * 32;

  // staging: thread (r0 = tid>>3, s0 = tid&7), one 16B K piece + one 16B V piece
  const int r0 = tid >> 3, s0 = tid & 7;

  f32x4 oacc[4];  // [dn]: O[i = wi*16+lgrp*4+v][d = dn*16+lrow], partial over wave's j-half
#pragma unroll
  for (int dn = 0; dn < 4; ++dn) oacc[dn] = (f32x4){0.f, 0.f, 0.f, 0.f};
  float lrun = 0.f;  // row-sum partial (lane's row qrow, wave's j-half)

  // prologue: load tile 0 + mask word, write LDS, barrier
  uint4 pfK = *(const uint4*)(Kp + (size_t)r0 * 64 + s0 * 8);
  uint4 pfV = *(const uint4*)(Vp + (size_t)r0 * NTOK + s0 * 8);
  unsigned long long mw = mword[0];
  *(uint4*)(Ks + r0 * 72 + s0 * 8) = pfK;
  *(uint4*)(Vs + r0 * 72 + s0 * 8) = pfV;
  __syncthreads();

  for (int jt = 0; jt < 32; ++jt) {
    // issue next tile's global loads; latency hides under this tile's compute
    unsigned long long mwn = 0ull;
    if (jt < 31) {
      const int jn = (jt + 1) * 64;
      pfK = *(const uint4*)(Kp + (size_t)(jn + r0) * 64 + s0 * 8);
      pfV = *(const uint4*)(Vp + (size_t)r0 * NTOK + jn + s0 * 8);
      mwn = mword[jt + 1];
    }

    // S^T = K Q^T over this wave's j-half; P packed straight into registers.
    // lane holds S[j = jt*64 + wj*32 + jsub*16 + lgrp*4 + r][i = qrow]
    uint32_t pk[2][2];  // [jsub][word]
#pragma unroll
    for (int jsub = 0; jsub < 2; ++jsub) {
      const int krow = (wj * 32 + jsub * 16 + lrow) * 72;
      bf16x8 kf0 = *(bf16x8*)(Ks + krow + lgrp * 8);
      bf16x8 kf1 = *(bf16x8*)(Ks + krow + 32 + lgrp * 8);
      f32x4 zz = (f32x4){0.f, 0.f, 0.f, 0.f};
      zz = MFMA16(kf0, qa[0], zz);
      zz = MFMA16(kf1, qa[1], zz);
      const uint32_t bits = (uint32_t)(mw >> (wj * 32 + jsub * 16 + lgrp * 4));
      float p0 = (bits & 1u) ? exp2f(zz[0]) : 0.f;
      float p1 = (bits & 2u) ? exp2f(zz[1]) : 0.f;
      float p2 = (bits & 4u) ? exp2f(zz[2]) : 0.f;
      float p3 = (bits & 8u) ? exp2f(zz[3]) : 0.f;
      lrun += (p0 + p1) + (p2 + p3);
      uint32_t w0, w1;
      asm("v_cvt_pk_bf16_f32 %0, %1, %2" : "=v"(w0) : "v"(p0), "v"(p1));
      asm("v_cvt_pk_bf16_f32 %0, %1, %2" : "=v"(w1) : "v"(p2), "v"(p3));
      pk[jsub][0] = w0;
      pk[jsub][1] = w1;
    }

    // O += P V: k-slot t<4 = jsub0 (j = wj*32+lgrp*4+t), t>=4 = jsub1 (+16);
    // V loaded in the SAME permuted order so the permutation cancels.
#pragma unroll
    for (int dn = 0; dn < 4; ++dn) {
      const int vrow = (dn * 16 + lrow) * 72 + wj * 32 + lgrp * 4;
      const uint2 v0 = *(const uint2*)(Vs + vrow);       // jsub0: 4 bf16
      const uint2 v1 = *(const uint2*)(Vs + vrow + 16);  // jsub1: 4 bf16
      u4bf8 vb;
      vb.u = (uint4){v0.x, v0.y, v1.x, v1.y};
      u4bf8 pa;
      pa.u = (uint4){pk[0][0], pk[0][1], pk[1][0], pk[1][1]};
      oacc[dn] = MFMA16(pa.h, vb.h, oacc[dn]);
    }

    if (jt < 31) {
      __syncthreads();  // all waves done reading Ks/Vs
      *(uint4*)(Ks + r0 * 72 + s0 * 8) = pfK;
      *(uint4*)(Vs + r0 * 72 + s0 * 8) = pfV;
      mw = mwn;
      __syncthreads();  // writes visible
    }
  }

  __syncthreads();  // done with Ks/Vs; smem becomes ored/lsum

  // ---- epilogue: reduce across the wj wave pair, normalize, store ----
  {
    float s = lrun;
    s += __shfl_xor(s, 16);
    s += __shfl_xor(s, 32);
    if (lane < 16) lsum[w * 16 + lane] = s;  // w = wi*2+wj
  }
  if (wj == 1) {
#pragma unroll
    for (int dn = 0; dn < 4; ++dn) ored[(wi * 4 + dn) * 64 + lane] = oacc[dn];
  }
  __syncthreads();

  if (wj == 0) {
    const int b = bh >> 3, h = bh & 7;
    const f32x4 la = *(const f32x4*)&lsum[(wi * 2 + 0) * 16 + lgrp * 4];
    const f32x4 lb = *(const f32x4*)&lsum[(wi * 2 + 1) * 16 + lgrp * 4];
    float inv[4];
#pragma unroll
    for (int v = 0; v < 4; ++v) inv[v] = 1.0f / (la[v] + lb[v]);
#pragma unroll
    for (int dn = 0; dn < 4; ++dn) {
      f32x4 s = oacc[dn] + ored[(wi * 4 + dn) * 64 + lane];
#pragma unroll
      for (int v = 0; v < 4; ++v) {
        int i = ibase + wi * 16 + lgrp * 4 + v;
        out[(size_t)(b * NTOK + i) * DIN + h * 64 + dn * 16 + lrow] = s[v] * inv[v];
      }
    }
  }
}

extern "C" void kernel_launch(void* const* d_in, const int* in_sizes, int n_in,
                              void* d_out, int out_size, void* d_ws, size_t ws_size,
                              hipStream_t stream) {
  const float* x   = (const float*)d_in[0];
  const float* adj = (const float*)d_in[1];
  const float* Wq  = (const float*)d_in[2];
  const float* bq  = (const float*)d_in[3];
  const float* Wk  = (const float*)d_in[4];
  const float* bk  = (const float*)d_in[5];
  const float* Wv  = (const float*)d_in[6];
  const float* bv  = (const float*)d_in[7];
  float* out = (float*)d_out;

  char* ws = (char*)d_ws;
  short* Qb = (short*)(ws);                          // 8 MB  [bh][n][d]
  short* Kb = (short*)(ws + (8u << 20));             // 8 MB  [bh][n][d]
  short* Vb = (short*)(ws + (16u << 20));            // 8 MB  [bh][d][n]
  short* Wt = (short*)(ws + (24u << 20));            // 1.5 MB [3][512][512]
  unsigned long long* m64 = (unsigned long long*)(ws + (26u << 20));  // 512 KB
  short* xb = (short*)d_out;  // 8 MB scratch inside the 16.8 MB output buffer;
                              // fully consumed by k_qkv before k_attn overwrites out.

  k_prep<<<21248, 256, 0, stream>>>(x, xb, Wq, Wk, Wv, Wt, adj, m64);
  k_qkv<<<dim3(64, 4, 3), 256, 0, stream>>>(xb, Wt, bq, bk, bv, Qb, Kb, Vb);
  k_attn<<<dim3(32, 32), 512, 0, stream>>>(Qb, Kb, Vb, m64, out);
}